// Round 22
// baseline (26.890 us; speedup 1.0000x reference)
//
#include <hip/hip_runtime.h>
#include <hip/hip_bf16.h>
#include <cstdint>

// GraphLoss single-kernel: fusion (16 wgs) + gold (240 wgs) + 16-step chain
// (wave 0 of wg 0, pure-LDS, zero per-step sync).
// result = sum(w*gold) + logsumexp over all source->sink paths of (-path weight).
//
// Pieces, all individually proven:
//  * fusion matmul  = R21 verbatim (bitwise-identical f32 products)
//  * pack layout    = R5 (word f=c*256+b*4+d packs P[8c+2d][b],P[8c+2d+1][b])
//  * chain body     = R17 consumer verbatim (absmax 0.0; slow there only due
//                     to flag spins, which are gone: W is fully LDS-resident)
//  * flag protocol  = R9/R12/R13 MAGIC (poison 0xAA != MAGIC; release/acquire
//                     agent scope; consumer resets to 0; stream serializes)
//  * DMA            = global_load_lds, LDS targets -> no register hazards;
//                     ONE vmcnt(0) drain, no counted-vmcnt arithmetic at all.
// wg 0 keeps its own product in LDS (LDS->LDS pack) - no global round trip.
//
// ws words: U[0..16) fusion flags | U[16..256) gold flags | F[256..496) gold
// partials | U[1024..1024+32768) wpk (16 blocks x 2048 words).
//
// Edge layout: e in [0,64): source->layer1 ; e = 64 + L*4096 + a*64 + b ;
// e = 258112 + j: layer64 node j -> sink.

typedef float v2f   __attribute__((ext_vector_type(2)));
typedef float f32x4 __attribute__((ext_vector_type(4)));
typedef unsigned int u32x4 __attribute__((ext_vector_type(4)));
typedef __attribute__((address_space(3))) unsigned int as3_u32;
typedef __attribute__((address_space(1))) const unsigned int as1_u32;

#define SINK_BASE (64 + 63 * 4096)   // 258112
#define NGOLD 240
#define MAGIC 0x5EC0FFEEu
#define LDSTR 68                     // padded staging row stride (f32 words)

__global__ __launch_bounds__(256, 1)
void fused_kernel(const int* __restrict__ g, const float* __restrict__ w,
                  float* __restrict__ wsF, float* __restrict__ out, int E) {
    __shared__ __align__(16) char LDSRAW[132096];
    float* Xs = (float*)(LDSRAW);                  // 17408 B
    float* Ys = (float*)(LDSRAW + 17408);
    float* Zs = (float*)(LDSRAW + 34816);
    unsigned int* ring = (unsigned int*)LDSRAW;    // 16 x 8192 B (reuses staging)
    float* ubuf0 = (float*)(LDSRAW + 131072);      // 64 f32
    float* ubuf1 = (float*)(LDSRAW + 131328);      // 64 f32
    float* gred  = (float*)(LDSRAW + 131584);      // 4 f32

    unsigned int* wsU = (unsigned int*)wsF;
    unsigned int* wpk = wsU + 1024;
    const int bid = blockIdx.x, t = threadIdx.x;
    const int wv = t >> 6, l = t & 63;

    if (bid >= 16) {
        // ---------------- gold partial (240 wgs) ----------------
        const int gid = bid - 16;
        const bool is64 = (g[1] == 0);
        float s = 0.f;
        for (int e = gid * 256 + t; e < E; e += NGOLD * 256) {
            const int idx = 3 * e + 2;
            const int gv = is64 ? g[2 * idx] : g[idx];
            s += w[e] * (float)gv;
        }
        #pragma unroll
        for (int dd = 1; dd < 64; dd <<= 1) s += __shfl_xor(s, dd, 64);
        if (l == 0) gred[wv] = s;
        __syncthreads();
        if (t == 0) {
            const float tt = gred[0] + gred[1] + gred[2] + gred[3];
            __hip_atomic_store(&wsF[256 + gid], tt, __ATOMIC_RELAXED,
                               __HIP_MEMORY_SCOPE_AGENT);
            __hip_atomic_store(&wsU[16 + gid], MAGIC, __ATOMIC_RELEASE,
                               __HIP_MEMORY_SCOPE_AGENT);
        }
        return;
    }

    // ---------------- fusion (wgs 0..15): P = prod of 4 (g15: 3) levels ----
    const int L0 = 4 * bid;
    const int ng = (bid == 15) ? 3 : 4;
    {
        const float* src = w + 64 + L0 * 4096;
        #pragma unroll
        for (int j = 0; j < 16; ++j) {
            const int idx = j * 256 + t;
            Xs[(idx >> 6) * LDSTR + (idx & 63)] = __expf(-src[idx]);
        }
    }
    float* cur = Xs;
    float* oth = Zs;
    const int rb = 4 * (t >> 4);
    const int c0 = 4 * (t & 15);

    #pragma unroll 1
    for (int m = 1; m < ng; ++m) {
        const float* src = w + 64 + (L0 + m) * 4096;
        #pragma unroll
        for (int j = 0; j < 16; ++j) {
            const int idx = j * 256 + t;
            Ys[(idx >> 6) * LDSTR + (idx & 63)] = __expf(-src[idx]);
        }
        __syncthreads();
        f32x4 a0 = {0,0,0,0}, a1 = {0,0,0,0}, a2 = {0,0,0,0}, a3 = {0,0,0,0};
        #pragma unroll 2
        for (int kb = 0; kb < 16; ++kb) {
            const f32x4 x0 = *(const f32x4*)&cur[(rb + 0) * LDSTR + 4 * kb];
            const f32x4 x1 = *(const f32x4*)&cur[(rb + 1) * LDSTR + 4 * kb];
            const f32x4 x2 = *(const f32x4*)&cur[(rb + 2) * LDSTR + 4 * kb];
            const f32x4 x3 = *(const f32x4*)&cur[(rb + 3) * LDSTR + 4 * kb];
            #pragma unroll
            for (int dk = 0; dk < 4; ++dk) {
                const f32x4 y = *(const f32x4*)&Ys[(4 * kb + dk) * LDSTR + c0];
                const f32x4 s0 = {x0[dk], x0[dk], x0[dk], x0[dk]};
                const f32x4 s1 = {x1[dk], x1[dk], x1[dk], x1[dk]};
                const f32x4 s2 = {x2[dk], x2[dk], x2[dk], x2[dk]};
                const f32x4 s3 = {x3[dk], x3[dk], x3[dk], x3[dk]};
                a0 = __builtin_elementwise_fma(s0, y, a0);
                a1 = __builtin_elementwise_fma(s1, y, a1);
                a2 = __builtin_elementwise_fma(s2, y, a2);
                a3 = __builtin_elementwise_fma(s3, y, a3);
            }
        }
        *(f32x4*)&oth[(rb + 0) * LDSTR + c0] = a0;
        *(f32x4*)&oth[(rb + 1) * LDSTR + c0] = a1;
        *(f32x4*)&oth[(rb + 2) * LDSTR + c0] = a2;
        *(f32x4*)&oth[(rb + 3) * LDSTR + c0] = a3;
        __syncthreads();
        float* tmp = cur; cur = oth; oth = tmp;
    }
    // bid 0..14: cur = Zs (3 swaps). bid 15: cur = Xs (2 swaps).

    // pack (R5 layout): word f = j*256 + t -> c=j, d=t&3, b=t>>2
    if (bid != 0) {
        #pragma unroll
        for (int j = 0; j < 8; ++j) {
            const int k0 = 8 * j + 2 * (t & 3);
            const int bcol = t >> 2;
            const float x0 = cur[k0 * LDSTR + bcol];
            const float x1 = cur[(k0 + 1) * LDSTR + bcol];
            uint32_t u0 = __float_as_uint(x0); u0 = (u0 + 0x7fffu + ((u0 >> 16) & 1u)) >> 16;
            uint32_t u1 = __float_as_uint(x1); u1 = (u1 + 0x7fffu + ((u1 >> 16) & 1u)) >> 16;
            wpk[bid * 2048 + j * 256 + t] = u0 | (u1 << 16);
        }
        __syncthreads();
        if (t == 0)
            __hip_atomic_store(&wsU[bid], MAGIC, __ATOMIC_RELEASE,
                               __HIP_MEMORY_SCOPE_AGENT);
        return;
    }

    // ---------------- wg 0: own product LDS->LDS into ring[0] ----------------
    // cur = Zs [34816,52224); ring block 0 = [0,8192) (dead Xs region).
    unsigned int pkw[8];
    #pragma unroll
    for (int j = 0; j < 8; ++j) {
        const int k0 = 8 * j + 2 * (t & 3);
        const int bcol = t >> 2;
        const float x0 = cur[k0 * LDSTR + bcol];
        const float x1 = cur[(k0 + 1) * LDSTR + bcol];
        uint32_t u0 = __float_as_uint(x0); u0 = (u0 + 0x7fffu + ((u0 >> 16) & 1u)) >> 16;
        uint32_t u1 = __float_as_uint(x1); u1 = (u1 + 0x7fffu + ((u1 >> 16) & 1u)) >> 16;
        pkw[j] = u0 | (u1 << 16);
    }
    __syncthreads();                 // all Zs reads done before ring writes land anywhere
    #pragma unroll
    for (int j = 0; j < 8; ++j) ring[j * 256 + t] = pkw[j];

    // chain init loads (issue early; compiler-managed waits)
    const float z1 = -w[l];
    const float wsink = w[SINK_BASE + l];

    // wait for fusion flags 1..15
    if (wv == 0 && l >= 1 && l < 16) {
        while (__hip_atomic_load(&wsU[l], __ATOMIC_ACQUIRE,
                                 __HIP_MEMORY_SCOPE_AGENT) != MAGIC)
            __builtin_amdgcn_s_sleep(1);
    }
    __syncthreads();                 // flags seen + ring[0] writes + Zs reads done
    if (t >= 1 && t < 16) wsU[t] = 0;   // reset for next launch

    // DMA blocks 1..15 from wpk into ring (LDS targets: no reg hazards)
    #pragma unroll 1
    for (int blk = 1; blk < 16; ++blk) {
        #pragma unroll
        for (int half = 0; half < 2; ++half) {
            const int idx = blk * 2048 + half * 1024 + (t << 2);
            __builtin_amdgcn_global_load_lds((as1_u32*)(wpk + idx),
                                             (as3_u32*)(ring + idx), 16, 0, 0);
        }
    }
    asm volatile("s_waitcnt vmcnt(0)" ::: "memory");
    __syncthreads();
    if (wv != 0) return;             // waves 1-3 done; wave 0 runs the chain

    // ---------------- chain: 16 steps, pure LDS, zero sync (R17 body) -------
    float LS = __int_as_float(__builtin_amdgcn_readfirstlane(__float_as_int(z1)));
    float uf = __expf(z1 - LS);      // u_1, u_1[0] = 1
    ubuf0[l] = uf;

    #pragma unroll 1
    for (int st = 0; st < 16; ++st) {
        const unsigned int* wslot = &ring[st * 2048];
        const f32x4* uq4 = (const f32x4*)((st & 1) ? ubuf1 : ubuf0);
        v2f acc0 = {0.f, 0.f}, acc1 = {0.f, 0.f};
        #pragma unroll
        for (int c = 0; c < 8; ++c) {
            const u32x4 wc = *(const u32x4*)&wslot[(c << 8) + (l << 2)];
            const f32x4 ua = uq4[2 * c];
            const f32x4 ub = uq4[2 * c + 1];
            v2f w0, w1, w2, w3, u01, u23, u45, u67;
            w0[0] = __uint_as_float(wc[0] << 16);
            w0[1] = __uint_as_float(wc[0] & 0xffff0000u);
            w1[0] = __uint_as_float(wc[1] << 16);
            w1[1] = __uint_as_float(wc[1] & 0xffff0000u);
            w2[0] = __uint_as_float(wc[2] << 16);
            w2[1] = __uint_as_float(wc[2] & 0xffff0000u);
            w3[0] = __uint_as_float(wc[3] << 16);
            w3[1] = __uint_as_float(wc[3] & 0xffff0000u);
            u01[0] = ua[0]; u01[1] = ua[1]; u23[0] = ua[2]; u23[1] = ua[3];
            u45[0] = ub[0]; u45[1] = ub[1]; u67[0] = ub[2]; u67[1] = ub[3];
            acc0 = __builtin_elementwise_fma(w0, u01, acc0);
            acc1 = __builtin_elementwise_fma(w1, u23, acc1);
            acc0 = __builtin_elementwise_fma(w2, u45, acc0);
            acc1 = __builtin_elementwise_fma(w3, u67, acc1);
        }
        const v2f at = acc0 + acc1;
        const float p = at[0] + at[1];           // full 64-term dot for b=l
        const float rho = __int_as_float(__builtin_amdgcn_readfirstlane(__float_as_int(p)));
        float rc;
        asm("v_rcp_f32 %0, %1" : "=v"(rc) : "v"(rho));
        uf = p * rc;                             // u_next, u_next[0] = 1
        LS += __logf(rho);                       // off critical path
        ((st & 1) ? ubuf0 : ubuf1)[l] = uf;
        // single wave: compiler inserts lgkmcnt for the LDS RAW; no barrier
    }

    // sink fold: m[b] = LS + log(uf) - wsink; lsexp over b
    float m = LS + __logf(uf) - wsink;
    float s = 1.0f;
    #pragma unroll
    for (int d = 1; d < 64; d <<= 1) {
        const float om = __shfl_xor(m, d, 64);
        const float os = __shfl_xor(s, d, 64);
        const float nm = fmaxf(m, om);
        s = __expf(m - nm) * s + __expf(om - nm) * os;
        m = nm;
    }
    const float vsink = m + __logf(s);

    // gold gather: fixed order (deterministic), flags reset after read
    float gv = 0.f;
    #pragma unroll 1
    for (int i = 0; i < 4; ++i) {
        const int gid = l + 64 * i;
        if (gid < NGOLD) {
            while (__hip_atomic_load(&wsU[16 + gid], __ATOMIC_ACQUIRE,
                                     __HIP_MEMORY_SCOPE_AGENT) != MAGIC)
                __builtin_amdgcn_s_sleep(2);
            gv += wsF[256 + gid];
            __hip_atomic_store(&wsU[16 + gid], 0u, __ATOMIC_RELAXED,
                               __HIP_MEMORY_SCOPE_AGENT);
        }
    }
    #pragma unroll
    for (int d = 1; d < 64; d <<= 1) gv += __shfl_xor(gv, d, 64);

    if (l == 0) out[0] = gv + vsink;
}

extern "C" void kernel_launch(void* const* d_in, const int* in_sizes, int n_in,
                              void* d_out, int out_size, void* d_ws, size_t ws_size,
                              hipStream_t stream) {
    const int*   g = (const int*)d_in[0];
    const float* w = (const float*)d_in[1];
    float* out     = (float*)d_out;
    float* ws      = (float*)d_ws;
    const int E = in_sizes[0] / 3;   // 258176

    fused_kernel<<<16 + NGOLD, 256, 0, stream>>>(g, w, ws, out, E);
}